// Round 17
// baseline (1081.775 us; speedup 1.0000x reference)
//
#include <hip/hip_runtime.h>
#include <stdint.h>

typedef unsigned int u32;
typedef unsigned short u16;
typedef __attribute__((ext_vector_type(8))) __bf16 bf16x8;
typedef __attribute__((ext_vector_type(4))) float f32x4;
typedef __attribute__((ext_vector_type(4))) u32 u32x4;
typedef __attribute__((ext_vector_type(2))) u32 u32x2;

#define NSTEPS 256
// ---- workspace layout ----
#define XB_BYTES   67108864u              // x as bf16: 512*256*256*2
#define SL_OFF     XB_BYTES               // h slots: 2 x [group][wgN][row][c16] bf16
#define GRP_BYTES   65536u                // 32 wgN * 2048B
#define SLOT_BYTES  524288u               // 8 groups
#define CNT_OFF    (SL_OFF + 2u * SLOT_BYTES)  // cnt[grp][j]: grp*1024 + j*256 (4 lines/grp)
// ---- LDS: fragment-linear weights ----
#define LDS_TOTAL 98304                   // 4*24*64*16

static __device__ __forceinline__ u16 f2bf(float f) {
  u32 u = __builtin_bit_cast(u32, f);
  return (u16)((u + 0x7fffu + ((u >> 16) & 1u)) >> 16);   // RNE
}
static __device__ __forceinline__ float bf2f(u16 h) {
  u32 u = ((u32)h) << 16;
  return __builtin_bit_cast(float, u);
}
static __device__ __forceinline__ float sigm(float x) {
  return __builtin_amdgcn_rcpf(1.f + __builtin_amdgcn_exp2f(-1.4426950408889634f * x));
}
static __device__ __forceinline__ float tanh_(float x) {
  return 1.f - 2.f * __builtin_amdgcn_rcpf(1.f + __builtin_amdgcn_exp2f(2.8853900817779268f * x));
}

// device-coherent primitives (proven transport: observed-atomic-then-load)
static __device__ __forceinline__ u32 poll_sc(const u32* p) {
  u32 v;
  asm volatile("global_load_dword %0, %1, off sc0 sc1\n\ts_waitcnt vmcnt(0)"
               : "=v"(v) : "v"(p) : "memory");
  return v;
}
// issue-only counter load (no wait) for pipelined polling
#define POLL_ISSUE(dst, addr) \
  asm volatile("global_load_dword %0, %1, off sc0 sc1" \
               : "=v"(dst) : "v"(addr) : "memory")
static __device__ __forceinline__ void st8_sc(void* p, u32x2 v) {
  asm volatile("global_store_dwordx2 %0, %1, off sc0 sc1" :: "v"(p), "v"(v) : "memory");
}
static __device__ __forceinline__ u32x4 ld16_sc_wait(const void* p) {
  u32x4 v;
  asm volatile("global_load_dwordx4 %0, %1, off sc0 sc1\n\ts_waitcnt vmcnt(0)"
               : "=v"(v) : "v"(p) : "memory");
  return v;
}
// issue 8 cached x loads (no wait)
static __device__ __forceinline__ void xissue(u32x4 x[8], const void* base) {
  asm volatile(
    "global_load_dwordx4 %0, %8, off offset:0\n\t"
    "global_load_dwordx4 %1, %8, off offset:64\n\t"
    "global_load_dwordx4 %2, %8, off offset:128\n\t"
    "global_load_dwordx4 %3, %8, off offset:192\n\t"
    "global_load_dwordx4 %4, %8, off offset:256\n\t"
    "global_load_dwordx4 %5, %8, off offset:320\n\t"
    "global_load_dwordx4 %6, %8, off offset:384\n\t"
    "global_load_dwordx4 %7, %8, off offset:448"
    : "=&v"(x[0]), "=&v"(x[1]), "=&v"(x[2]), "=&v"(x[3]),
      "=&v"(x[4]), "=&v"(x[5]), "=&v"(x[6]), "=&v"(x[7])
    : "v"(base) : "memory");
}
// issue 16 device-coherent h-fragment loads (no wait); stride 4096 B (kc)
static __device__ __forceinline__ void aissue(u32x4 s[16], const char* b) {
  asm volatile(
    "global_load_dwordx4 %0, %16, off sc0 sc1\n\t"
    "global_load_dwordx4 %1, %17, off sc0 sc1\n\t"
    "global_load_dwordx4 %2, %18, off sc0 sc1\n\t"
    "global_load_dwordx4 %3, %19, off sc0 sc1\n\t"
    "global_load_dwordx4 %4, %20, off sc0 sc1\n\t"
    "global_load_dwordx4 %5, %21, off sc0 sc1\n\t"
    "global_load_dwordx4 %6, %22, off sc0 sc1\n\t"
    "global_load_dwordx4 %7, %23, off sc0 sc1\n\t"
    "global_load_dwordx4 %8, %24, off sc0 sc1\n\t"
    "global_load_dwordx4 %9, %25, off sc0 sc1\n\t"
    "global_load_dwordx4 %10, %26, off sc0 sc1\n\t"
    "global_load_dwordx4 %11, %27, off sc0 sc1\n\t"
    "global_load_dwordx4 %12, %28, off sc0 sc1\n\t"
    "global_load_dwordx4 %13, %29, off sc0 sc1\n\t"
    "global_load_dwordx4 %14, %30, off sc0 sc1\n\t"
    "global_load_dwordx4 %15, %31, off sc0 sc1"
    : "=&v"(s[0]), "=&v"(s[1]), "=&v"(s[2]), "=&v"(s[3]),
      "=&v"(s[4]), "=&v"(s[5]), "=&v"(s[6]), "=&v"(s[7]),
      "=&v"(s[8]), "=&v"(s[9]), "=&v"(s[10]), "=&v"(s[11]),
      "=&v"(s[12]), "=&v"(s[13]), "=&v"(s[14]), "=&v"(s[15])
    : "v"(b), "v"(b + 4096), "v"(b + 8192), "v"(b + 12288),
      "v"(b + 16384), "v"(b + 20480), "v"(b + 24576), "v"(b + 28672),
      "v"(b + 32768), "v"(b + 36864), "v"(b + 40960), "v"(b + 45056),
      "v"(b + 49152), "v"(b + 53248), "v"(b + 57344), "v"(b + 61440)
    : "memory");
}
#define AWAIT(N) do { asm volatile("s_waitcnt vmcnt(" #N ")" ::: "memory"); \
                      __builtin_amdgcn_sched_barrier(0); } while (0)

__global__ void cvt_x(const float* __restrict__ x, u16* __restrict__ xb) {
  int i = blockIdx.x * 256 + threadIdx.x;          // one float4 per thread
  float4 v = ((const float4*)x)[i];
  ushort4 o;
  o.x = f2bf(v.x); o.y = f2bf(v.y); o.z = f2bf(v.z); o.w = f2bf(v.w);
  ((ushort4*)xb)[i] = o;
}

// 256 WGs: group = wg&7 (batch rows [grp*64,+64)), wgN = wg>>3 (hidden cols
// [wgN*16,+16) of all 4 gates). Swapped MFMA (D = W·X^T). R17 delta vs R16:
// the x_{t+1} prefetch is issued RIGHT AFTER the x-part MFMA loop (its last
// xreg use) — the x RTT hides under the h-part MFMAs + gates, and the
// post-store AWAIT(0) drains store+x together. h-chunk waits shift +8
// (AWAIT 20/16/12/8) since the 8 x loads are newest in the vmcnt FIFO.
// Poll still starts with a clean vmcnt. Signal protocol unchanged.
__global__ void __launch_bounds__(256, 1) lstm_main(
    const u16* __restrict__ xb,
    const float* __restrict__ W_ih, const float* __restrict__ W_hh,
    const float* __restrict__ b_ih, const float* __restrict__ b_hh,
    const float* __restrict__ W_out, const float* __restrict__ b_out,
    float* __restrict__ out, char* __restrict__ ws)
{
  __shared__ char smem[LDS_TOTAL];
  __shared__ u32 step_flag;
  const int tid = threadIdx.x;
  const int wg  = blockIdx.x;
  const int grp = wg & 7;
  const int wgN = wg >> 3;
  const int lane = tid & 63;
  const int wv   = tid >> 6;
  const int cc = lane & 15;
  const int hi = lane >> 4;

  if (tid == 0) step_flag = 0;

  // ---- one-time: weight slice -> LDS, fragment-linear (conflict-free) ----
  {
    const int lc = lane & 15, hh = lane >> 4;
    #pragma unroll
    for (int nt = 0; nt < 4; ++nt)
      #pragma unroll
      for (int it = 0; it < 6; ++it) {
        int kcc = wv + it * 4;                  // 0..23
        int n = nt * 512 + wgN * 16 + lc;
        int k = kcc * 32 + hh * 8;
        float4 v0, v1;
        if (kcc < 8) {
          v0 = *(const float4*)(W_ih + n * 256 + k);
          v1 = *(const float4*)(W_ih + n * 256 + k + 4);
        } else {
          int k2 = k - 256;
          v0 = *(const float4*)(W_hh + n * 512 + k2);
          v1 = *(const float4*)(W_hh + n * 512 + k2 + 4);
        }
        u32x4 g;
        g[0] = (u32)f2bf(v0.x) | ((u32)f2bf(v0.y) << 16);
        g[1] = (u32)f2bf(v0.z) | ((u32)f2bf(v0.w) << 16);
        g[2] = (u32)f2bf(v1.x) | ((u32)f2bf(v1.y) << 16);
        g[3] = (u32)f2bf(v1.z) | ((u32)f2bf(v1.w) << 16);
        *(u32x4*)(smem + ((nt * 24 + kcc) * 64 + lane) * 16) = g;
      }
  }

  float bvn[4][4];
  #pragma unroll
  for (int nt = 0; nt < 4; ++nt)
    #pragma unroll
    for (int r = 0; r < 4; ++r) {
      int n = nt * 512 + wgN * 16 + hi * 4 + r;
      bvn[nt][r] = b_ih[n] + b_hh[n];
    }

  u32* cnt = (u32*)(ws + CNT_OFF + grp * 1024);  // 4 lines, 256B apart
  const u32* mypoll = cnt + (lane & 3) * 64;     // lane j polls line j&3
  u32* mysig = cnt + (wgN & 3) * 64;             // producer's signal line
  char* slices = ws + SL_OFF;
  const char* grpsl = slices + (size_t)grp * GRP_BYTES;

  const u16* xrow = xb + (size_t)(grp * 64 + wv * 16 + cc) * 65536 + hi * 8;
  // A-fragment per-lane base inside slot (stride 4096 per kc)
  const int afrag = (hi >> 1) * 2048 + (wv * 16 + cc) * 32 + (hi & 1) * 16;

  __syncthreads();

  // ---- pin h-part weight fragments in 256 regs (kc 8..23 of full row) ----
  bf16x8 bh[16][4];
  #pragma unroll
  for (int kc = 0; kc < 16; ++kc)
    #pragma unroll
    for (int nt = 0; nt < 4; ++nt)
      bh[kc][nt] = *(const bf16x8*)(smem + ((nt * 24 + kc + 8) * 64 + lane) * 16);
  #pragma unroll
  for (int kc = 0; kc < 16; ++kc)
    #pragma unroll
    for (int nt = 0; nt < 4; ++nt)
      asm volatile("" : "+v"(bh[kc][nt]));      // opaque: forbid remat, force regs

  float cst[4] = {0.f, 0.f, 0.f, 0.f};          // fp32 cell state

  u32x4 xreg[8];
  xissue(xreg, xrow);                            // prefetch x_0
  AWAIT(0);                                      // drain: polls start clean

  #pragma unroll 1
  for (int t = 0; t < NSTEPS; ++t) {
    if (t > 0) {
      u32 tgt = 8u * (u32)t;                     // per-line target (8 producers)
      if (wv == 0) {
        // ---- 2-deep pipelined poll, clean vmcnt ----
        u32 pa, pb;
        POLL_ISSUE(pa, mypoll);
        POLL_ISSUE(pb, mypoll);
        int guard = 0;
        for (;;) {
          AWAIT(1);                              // pa's load complete
          if (__all((int)(pa >= tgt))) break;    // stale-reg read: monotone-safe
          POLL_ISSUE(pa, mypoll);
          AWAIT(1);                              // pb's load complete
          if (__all((int)(pb >= tgt))) break;
          POLL_ISSUE(pb, mypoll);
          if (++guard > (1 << 20)) break;        // watchdog: fail fast, never hang
        }
        AWAIT(0);                                // drain the other in-flight poll
        if (lane == 0)
          __hip_atomic_store(&step_flag, (u32)t, __ATOMIC_RELAXED,
                             __HIP_MEMORY_SCOPE_WORKGROUP);
      } else {
        int guard = 0;
        while (__hip_atomic_load(&step_flag, __ATOMIC_RELAXED,
                                 __HIP_MEMORY_SCOPE_WORKGROUP) < (u32)t) {
          __builtin_amdgcn_s_sleep(1);
          if (++guard > (1 << 20)) break;
        }
      }
    }

    // ---- issue 16 direct h-fragment loads (L3 RTT hides under x-part) ----
    // at t=0 this reads slot 1 (memset to zero each launch) => h_-1 = 0 exactly
    const char* rds = grpsl + (size_t)((t & 1) ^ 1) * SLOT_BYTES;
    u32x4 av[16];
    aissue(av, rds + afrag);

    // x already in regs (drained last step); x-part while av in flight
    f32x4 acc[4] = {};
    #pragma unroll
    for (int kc = 0; kc < 8; ++kc) {
      bf16x8 b = __builtin_bit_cast(bf16x8, xreg[kc]);
      #pragma unroll
      for (int nt = 0; nt < 4; ++nt) {
        bf16x8 a = *(const bf16x8*)(smem + ((nt * 24 + kc) * 64 + lane) * 16);
        acc[nt] = __builtin_amdgcn_mfma_f32_16x16x32_bf16(a, b, acc[nt], 0, 0, 0);
      }
    }

    // ---- issue x_{t+1} NOW (last xreg use was above); RTT hides under h-part
    {
      size_t tn = (t + 1 < NSTEPS) ? (size_t)(t + 1) : (size_t)t;
      xissue(xreg, xrow + tn * 256);             // 8 newest entries in vmcnt FIFO
    }

    // ---- h-part from pinned weights; counts shifted +8 for in-flight x ----
    AWAIT(20);
    #pragma unroll
    for (int kc = 0; kc < 4; ++kc) {
      bf16x8 b = __builtin_bit_cast(bf16x8, av[kc]);
      #pragma unroll
      for (int nt = 0; nt < 4; ++nt)
        acc[nt] = __builtin_amdgcn_mfma_f32_16x16x32_bf16(bh[kc][nt], b, acc[nt], 0, 0, 0);
    }
    AWAIT(16);
    #pragma unroll
    for (int kc = 4; kc < 8; ++kc) {
      bf16x8 b = __builtin_bit_cast(bf16x8, av[kc]);
      #pragma unroll
      for (int nt = 0; nt < 4; ++nt)
        acc[nt] = __builtin_amdgcn_mfma_f32_16x16x32_bf16(bh[kc][nt], b, acc[nt], 0, 0, 0);
    }
    AWAIT(12);
    #pragma unroll
    for (int kc = 8; kc < 12; ++kc) {
      bf16x8 b = __builtin_bit_cast(bf16x8, av[kc]);
      #pragma unroll
      for (int nt = 0; nt < 4; ++nt)
        acc[nt] = __builtin_amdgcn_mfma_f32_16x16x32_bf16(bh[kc][nt], b, acc[nt], 0, 0, 0);
    }
    AWAIT(8);
    #pragma unroll
    for (int kc = 12; kc < 16; ++kc) {
      bf16x8 b = __builtin_bit_cast(bf16x8, av[kc]);
      #pragma unroll
      for (int nt = 0; nt < 4; ++nt)
        acc[nt] = __builtin_amdgcn_mfma_f32_16x16x32_bf16(bh[kc][nt], b, acc[nt], 0, 0, 0);
    }

    // ---- gates (lane: batch cc, cols hi*4+0..3), pack, ONE dwordx2 store ----
    char* wdst = slices + (size_t)(t & 1) * SLOT_BYTES + grp * GRP_BYTES + wgN * 2048;
    u32 plo = 0, phi2 = 0;
    #pragma unroll
    for (int r = 0; r < 4; ++r) {
      float gi = acc[0][r] + bvn[0][r];
      float gf = acc[1][r] + bvn[1][r];
      float gg = acc[2][r] + bvn[2][r];
      float go = acc[3][r] + bvn[3][r];
      float ii = sigm(gi), ff = sigm(gf), g2 = tanh_(gg), oo = sigm(go);
      float cn = ff * cst[r] + ii * g2;
      cst[r] = cn;
      float hn = oo * tanh_(cn);
      u32 hb = (u32)f2bf(hn);
      if (r < 2) plo |= hb << (16 * r);
      else       phi2 |= hb << (16 * (r - 2));
    }
    u32x2 pk; pk[0] = plo; pk[1] = phi2;
    st8_sc(wdst + (wv * 16 + cc) * 32 + hi * 8, pk);

    AWAIT(0);                                    // drain store + x together
    __syncthreads();
    if (tid == 0) atomicAdd(mysig, 1u);          // signal on spread line
  }

  // ---- head: one WG per group computes out = h_T @ W_out^T + b_out ----
  if (wgN == 0) {
    {
      const u32* hp = cnt + (lane & 3) * 64;
      int guard = 0;
      for (;;) {
        u32 v = poll_sc(hp);
        if (__all((int)(v >= 8u * NSTEPS))) break;
        if (++guard > (1 << 20)) break;
      }
    }
    const char* src = grpsl + SLOT_BYTES;        // slot 255&1 = 1
    int b = tid >> 2, q = tid & 3;
    float s = 0.f;
    #pragma unroll
    for (int j16 = 0; j16 < 8; ++j16) {
      int nblk = q * 8 + j16;                    // wgN' block
      const char* p = src + nblk * 2048 + b * 32;
      u32x4 w0 = ld16_sc_wait(p);
      u32x4 w1 = ld16_sc_wait(p + 16);
      #pragma unroll
      for (int d = 0; d < 4; ++d) {
        int jb = q * 128 + j16 * 16 + d * 2;
        s += bf2f((u16)(w0[d] & 0xffff)) * W_out[jb];
        s += bf2f((u16)(w0[d] >> 16))    * W_out[jb + 1];
        s += bf2f((u16)(w1[d] & 0xffff)) * W_out[jb + 8];
        s += bf2f((u16)(w1[d] >> 16))    * W_out[jb + 9];
      }
    }
    s += __shfl_xor(s, 1);
    s += __shfl_xor(s, 2);
    if (q == 0) out[grp * 64 + b] = s + b_out[0];
  }
}

extern "C" void kernel_launch(void* const* d_in, const int* in_sizes, int n_in,
                              void* d_out, int out_size, void* d_ws, size_t ws_size,
                              hipStream_t stream) {
  (void)in_sizes; (void)n_in; (void)out_size; (void)ws_size;
  const float* x     = (const float*)d_in[0];
  const float* W_ih  = (const float*)d_in[1];
  const float* W_hh  = (const float*)d_in[2];
  const float* b_ih  = (const float*)d_in[3];
  const float* b_hh  = (const float*)d_in[4];
  const float* W_out = (const float*)d_in[5];
  const float* b_out = (const float*)d_in[6];
  char* ws = (char*)d_ws;

  // zero h-exchange slots + spread counters (re-runs every graph replay)
  hipMemsetAsync(ws + SL_OFF, 0, 2u * SLOT_BYTES + 8192u, stream);
  cvt_x<<<32768, 256, 0, stream>>>(x, (u16*)ws);
  lstm_main<<<256, 256, 0, stream>>>((const u16*)ws, W_ih, W_hh, b_ih, b_hh,
                                     W_out, b_out, (float*)d_out, ws);
}

// Round 18
// 970.374 us; speedup vs baseline: 1.1148x; 1.1148x over previous
//
#include <hip/hip_runtime.h>
#include <stdint.h>

typedef unsigned int u32;
typedef unsigned short u16;
typedef __attribute__((ext_vector_type(8))) __bf16 bf16x8;
typedef __attribute__((ext_vector_type(4))) float f32x4;
typedef __attribute__((ext_vector_type(4))) u32 u32x4;
typedef __attribute__((ext_vector_type(2))) u32 u32x2;

#define NSTEPS 256
// ---- workspace layout ----
#define XB_BYTES   67108864u              // x as bf16: 512*256*256*2
#define SL_OFF     XB_BYTES               // h slots: 2 x [group][wgN][row][c16] bf16
#define GRP_BYTES   65536u                // 32 wgN * 2048B
#define SLOT_BYTES  524288u               // 8 groups
#define CNT_OFF    (SL_OFF + 2u * SLOT_BYTES)  // cnt[grp][j]: grp*1024 + j*256 (4 lines/grp)
// ---- LDS: fragment-linear weights ----
#define LDS_TOTAL 98304                   // 4*24*64*16

static __device__ __forceinline__ u16 f2bf(float f) {
  u32 u = __builtin_bit_cast(u32, f);
  return (u16)((u + 0x7fffu + ((u >> 16) & 1u)) >> 16);   // RNE
}
static __device__ __forceinline__ float bf2f(u16 h) {
  u32 u = ((u32)h) << 16;
  return __builtin_bit_cast(float, u);
}
static __device__ __forceinline__ float sigm(float x) {
  return __builtin_amdgcn_rcpf(1.f + __builtin_amdgcn_exp2f(-1.4426950408889634f * x));
}
static __device__ __forceinline__ float tanh_(float x) {
  return 1.f - 2.f * __builtin_amdgcn_rcpf(1.f + __builtin_amdgcn_exp2f(2.8853900817779268f * x));
}

// device-coherent primitives (proven transport: observed-atomic-then-load)
static __device__ __forceinline__ u32 poll_sc(const u32* p) {
  u32 v;
  asm volatile("global_load_dword %0, %1, off sc0 sc1\n\ts_waitcnt vmcnt(0)"
               : "=v"(v) : "v"(p) : "memory");
  return v;
}
// issue-only counter load (no wait) for pipelined polling
#define POLL_ISSUE(dst, addr) \
  asm volatile("global_load_dword %0, %1, off sc0 sc1" \
               : "=v"(dst) : "v"(addr) : "memory")
static __device__ __forceinline__ void st8_sc(void* p, u32x2 v) {
  asm volatile("global_store_dwordx2 %0, %1, off sc0 sc1" :: "v"(p), "v"(v) : "memory");
}
static __device__ __forceinline__ u32x4 ld16_sc_wait(const void* p) {
  u32x4 v;
  asm volatile("global_load_dwordx4 %0, %1, off sc0 sc1\n\ts_waitcnt vmcnt(0)"
               : "=v"(v) : "v"(p) : "memory");
  return v;
}
// issue 8 cached x loads (no wait)
static __device__ __forceinline__ void xissue(u32x4 x[8], const void* base) {
  asm volatile(
    "global_load_dwordx4 %0, %8, off offset:0\n\t"
    "global_load_dwordx4 %1, %8, off offset:64\n\t"
    "global_load_dwordx4 %2, %8, off offset:128\n\t"
    "global_load_dwordx4 %3, %8, off offset:192\n\t"
    "global_load_dwordx4 %4, %8, off offset:256\n\t"
    "global_load_dwordx4 %5, %8, off offset:320\n\t"
    "global_load_dwordx4 %6, %8, off offset:384\n\t"
    "global_load_dwordx4 %7, %8, off offset:448"
    : "=&v"(x[0]), "=&v"(x[1]), "=&v"(x[2]), "=&v"(x[3]),
      "=&v"(x[4]), "=&v"(x[5]), "=&v"(x[6]), "=&v"(x[7])
    : "v"(base) : "memory");
}
// issue 16 device-coherent h-fragment loads (no wait); stride 4096 B (kc)
static __device__ __forceinline__ void aissue(u32x4 s[16], const char* b) {
  asm volatile(
    "global_load_dwordx4 %0, %16, off sc0 sc1\n\t"
    "global_load_dwordx4 %1, %17, off sc0 sc1\n\t"
    "global_load_dwordx4 %2, %18, off sc0 sc1\n\t"
    "global_load_dwordx4 %3, %19, off sc0 sc1\n\t"
    "global_load_dwordx4 %4, %20, off sc0 sc1\n\t"
    "global_load_dwordx4 %5, %21, off sc0 sc1\n\t"
    "global_load_dwordx4 %6, %22, off sc0 sc1\n\t"
    "global_load_dwordx4 %7, %23, off sc0 sc1\n\t"
    "global_load_dwordx4 %8, %24, off sc0 sc1\n\t"
    "global_load_dwordx4 %9, %25, off sc0 sc1\n\t"
    "global_load_dwordx4 %10, %26, off sc0 sc1\n\t"
    "global_load_dwordx4 %11, %27, off sc0 sc1\n\t"
    "global_load_dwordx4 %12, %28, off sc0 sc1\n\t"
    "global_load_dwordx4 %13, %29, off sc0 sc1\n\t"
    "global_load_dwordx4 %14, %30, off sc0 sc1\n\t"
    "global_load_dwordx4 %15, %31, off sc0 sc1"
    : "=&v"(s[0]), "=&v"(s[1]), "=&v"(s[2]), "=&v"(s[3]),
      "=&v"(s[4]), "=&v"(s[5]), "=&v"(s[6]), "=&v"(s[7]),
      "=&v"(s[8]), "=&v"(s[9]), "=&v"(s[10]), "=&v"(s[11]),
      "=&v"(s[12]), "=&v"(s[13]), "=&v"(s[14]), "=&v"(s[15])
    : "v"(b), "v"(b + 4096), "v"(b + 8192), "v"(b + 12288),
      "v"(b + 16384), "v"(b + 20480), "v"(b + 24576), "v"(b + 28672),
      "v"(b + 32768), "v"(b + 36864), "v"(b + 40960), "v"(b + 45056),
      "v"(b + 49152), "v"(b + 53248), "v"(b + 57344), "v"(b + 61440)
    : "memory");
}
#define AWAIT(N) do { asm volatile("s_waitcnt vmcnt(" #N ")" ::: "memory"); \
                      __builtin_amdgcn_sched_barrier(0); } while (0)

__global__ void cvt_x(const float* __restrict__ x, u16* __restrict__ xb) {
  int i = blockIdx.x * 256 + threadIdx.x;          // one float4 per thread
  float4 v = ((const float4*)x)[i];
  ushort4 o;
  o.x = f2bf(v.x); o.y = f2bf(v.y); o.z = f2bf(v.z); o.w = f2bf(v.w);
  ((ushort4*)xb)[i] = o;
}

// 256 WGs: group = wg&7 (batch rows [grp*64,+64)), wgN = wg>>3 (hidden cols
// [wgN*16,+16) of all 4 gates). Swapped MFMA (D = W·X^T). R18 delta vs R16:
// the serial AWAIT(0) after the post-signal xissue is REMOVED. The 8 x loads
// ride as the OLDEST vmcnt entries into the next step: wave 0's first poll
// AWAIT(1) drains them overlapped with the first counter sample's RTT;
// waves 1-3 drain with one AWAIT(0) after the LDS-flag spin (free — x has
// been in flight for the whole producer wait). Signal protocol unchanged.
__global__ void __launch_bounds__(256, 1) lstm_main(
    const u16* __restrict__ xb,
    const float* __restrict__ W_ih, const float* __restrict__ W_hh,
    const float* __restrict__ b_ih, const float* __restrict__ b_hh,
    const float* __restrict__ W_out, const float* __restrict__ b_out,
    float* __restrict__ out, char* __restrict__ ws)
{
  __shared__ char smem[LDS_TOTAL];
  __shared__ u32 step_flag;
  const int tid = threadIdx.x;
  const int wg  = blockIdx.x;
  const int grp = wg & 7;
  const int wgN = wg >> 3;
  const int lane = tid & 63;
  const int wv   = tid >> 6;
  const int cc = lane & 15;
  const int hi = lane >> 4;

  if (tid == 0) step_flag = 0;

  // ---- one-time: weight slice -> LDS, fragment-linear (conflict-free) ----
  {
    const int lc = lane & 15, hh = lane >> 4;
    #pragma unroll
    for (int nt = 0; nt < 4; ++nt)
      #pragma unroll
      for (int it = 0; it < 6; ++it) {
        int kcc = wv + it * 4;                  // 0..23
        int n = nt * 512 + wgN * 16 + lc;
        int k = kcc * 32 + hh * 8;
        float4 v0, v1;
        if (kcc < 8) {
          v0 = *(const float4*)(W_ih + n * 256 + k);
          v1 = *(const float4*)(W_ih + n * 256 + k + 4);
        } else {
          int k2 = k - 256;
          v0 = *(const float4*)(W_hh + n * 512 + k2);
          v1 = *(const float4*)(W_hh + n * 512 + k2 + 4);
        }
        u32x4 g;
        g[0] = (u32)f2bf(v0.x) | ((u32)f2bf(v0.y) << 16);
        g[1] = (u32)f2bf(v0.z) | ((u32)f2bf(v0.w) << 16);
        g[2] = (u32)f2bf(v1.x) | ((u32)f2bf(v1.y) << 16);
        g[3] = (u32)f2bf(v1.z) | ((u32)f2bf(v1.w) << 16);
        *(u32x4*)(smem + ((nt * 24 + kcc) * 64 + lane) * 16) = g;
      }
  }

  float bvn[4][4];
  #pragma unroll
  for (int nt = 0; nt < 4; ++nt)
    #pragma unroll
    for (int r = 0; r < 4; ++r) {
      int n = nt * 512 + wgN * 16 + hi * 4 + r;
      bvn[nt][r] = b_ih[n] + b_hh[n];
    }

  u32* cnt = (u32*)(ws + CNT_OFF + grp * 1024);  // 4 lines, 256B apart
  const u32* mypoll = cnt + (lane & 3) * 64;     // lane j polls line j&3
  u32* mysig = cnt + (wgN & 3) * 64;             // producer's signal line
  char* slices = ws + SL_OFF;
  const char* grpsl = slices + (size_t)grp * GRP_BYTES;

  const u16* xrow = xb + (size_t)(grp * 64 + wv * 16 + cc) * 65536 + hi * 8;
  // A-fragment per-lane base inside slot (stride 4096 per kc)
  const int afrag = (hi >> 1) * 2048 + (wv * 16 + cc) * 32 + (hi & 1) * 16;

  __syncthreads();

  // ---- pin h-part weight fragments in 256 regs (kc 8..23 of full row) ----
  bf16x8 bh[16][4];
  #pragma unroll
  for (int kc = 0; kc < 16; ++kc)
    #pragma unroll
    for (int nt = 0; nt < 4; ++nt)
      bh[kc][nt] = *(const bf16x8*)(smem + ((nt * 24 + kc + 8) * 64 + lane) * 16);
  #pragma unroll
  for (int kc = 0; kc < 16; ++kc)
    #pragma unroll
    for (int nt = 0; nt < 4; ++nt)
      asm volatile("" : "+v"(bh[kc][nt]));      // opaque: forbid remat, force regs

  float cst[4] = {0.f, 0.f, 0.f, 0.f};          // fp32 cell state

  u32x4 xreg[8];
  xissue(xreg, xrow);                            // prefetch x_0
  AWAIT(0);                                      // prologue drain (t=0 clean)

  #pragma unroll 1
  for (int t = 0; t < NSTEPS; ++t) {
    if (t > 0) {
      u32 tgt = 8u * (u32)t;                     // per-line target (8 producers)
      if (wv == 0) {
        // ---- 2-deep pipelined poll; first AWAIT(1) also drains the 8
        // in-flight x loads (oldest FIFO entries), overlapped with pa's RTT ----
        u32 pa, pb;
        POLL_ISSUE(pa, mypoll);
        POLL_ISSUE(pb, mypoll);
        int guard = 0;
        for (;;) {
          AWAIT(1);                              // pa complete (+x on first iter)
          if (__all((int)(pa >= tgt))) break;    // stale-reg read: monotone-safe
          POLL_ISSUE(pa, mypoll);
          AWAIT(1);                              // pb complete
          if (__all((int)(pb >= tgt))) break;
          POLL_ISSUE(pb, mypoll);
          if (++guard > (1 << 20)) break;        // watchdog: fail fast, never hang
        }
        AWAIT(0);                                // drain other in-flight poll
        if (lane == 0)
          __hip_atomic_store(&step_flag, (u32)t, __ATOMIC_RELAXED,
                             __HIP_MEMORY_SCOPE_WORKGROUP);
      } else {
        int guard = 0;
        while (__hip_atomic_load(&step_flag, __ATOMIC_RELAXED,
                                 __HIP_MEMORY_SCOPE_WORKGROUP) < (u32)t) {
          __builtin_amdgcn_s_sleep(1);
          if (++guard > (1 << 20)) break;
        }
        AWAIT(0);                                // drain x (in flight whole wait: free)
      }
    }

    // ---- issue 16 direct h-fragment loads (clean FIFO on every wave) ----
    // at t=0 this reads slot 1 (memset to zero each launch) => h_-1 = 0 exactly
    const char* rds = grpsl + (size_t)((t & 1) ^ 1) * SLOT_BYTES;
    u32x4 av[16];
    aissue(av, rds + afrag);

    // x already in regs; x-part while av in flight
    f32x4 acc[4] = {};
    #pragma unroll
    for (int kc = 0; kc < 8; ++kc) {
      bf16x8 b = __builtin_bit_cast(bf16x8, xreg[kc]);
      #pragma unroll
      for (int nt = 0; nt < 4; ++nt) {
        bf16x8 a = *(const bf16x8*)(smem + ((nt * 24 + kc) * 64 + lane) * 16);
        acc[nt] = __builtin_amdgcn_mfma_f32_16x16x32_bf16(a, b, acc[nt], 0, 0, 0);
      }
    }

    // ---- h-part from pinned weights, counted-vmcnt chunks ----
    AWAIT(12);
    #pragma unroll
    for (int kc = 0; kc < 4; ++kc) {
      bf16x8 b = __builtin_bit_cast(bf16x8, av[kc]);
      #pragma unroll
      for (int nt = 0; nt < 4; ++nt)
        acc[nt] = __builtin_amdgcn_mfma_f32_16x16x32_bf16(bh[kc][nt], b, acc[nt], 0, 0, 0);
    }
    AWAIT(8);
    #pragma unroll
    for (int kc = 4; kc < 8; ++kc) {
      bf16x8 b = __builtin_bit_cast(bf16x8, av[kc]);
      #pragma unroll
      for (int nt = 0; nt < 4; ++nt)
        acc[nt] = __builtin_amdgcn_mfma_f32_16x16x32_bf16(bh[kc][nt], b, acc[nt], 0, 0, 0);
    }
    AWAIT(4);
    #pragma unroll
    for (int kc = 8; kc < 12; ++kc) {
      bf16x8 b = __builtin_bit_cast(bf16x8, av[kc]);
      #pragma unroll
      for (int nt = 0; nt < 4; ++nt)
        acc[nt] = __builtin_amdgcn_mfma_f32_16x16x32_bf16(bh[kc][nt], b, acc[nt], 0, 0, 0);
    }
    AWAIT(0);
    #pragma unroll
    for (int kc = 12; kc < 16; ++kc) {
      bf16x8 b = __builtin_bit_cast(bf16x8, av[kc]);
      #pragma unroll
      for (int nt = 0; nt < 4; ++nt)
        acc[nt] = __builtin_amdgcn_mfma_f32_16x16x32_bf16(bh[kc][nt], b, acc[nt], 0, 0, 0);
    }

    // ---- gates (lane: batch cc, cols hi*4+0..3), pack, ONE dwordx2 store ----
    char* wdst = slices + (size_t)(t & 1) * SLOT_BYTES + grp * GRP_BYTES + wgN * 2048;
    u32 plo = 0, phi2 = 0;
    #pragma unroll
    for (int r = 0; r < 4; ++r) {
      float gi = acc[0][r] + bvn[0][r];
      float gf = acc[1][r] + bvn[1][r];
      float gg = acc[2][r] + bvn[2][r];
      float go = acc[3][r] + bvn[3][r];
      float ii = sigm(gi), ff = sigm(gf), g2 = tanh_(gg), oo = sigm(go);
      float cn = ff * cst[r] + ii * g2;
      cst[r] = cn;
      float hn = oo * tanh_(cn);
      u32 hb = (u32)f2bf(hn);
      if (r < 2) plo |= hb << (16 * r);
      else       phi2 |= hb << (16 * (r - 2));
    }
    u32x2 pk; pk[0] = plo; pk[1] = phi2;
    st8_sc(wdst + (wv * 16 + cc) * 32 + hi * 8, pk);

    AWAIT(0);                                    // own store at coherence point
    __syncthreads();
    if (tid == 0) atomicAdd(mysig, 1u);          // signal on spread line
    if (t + 1 < NSTEPS)
      xissue(xreg, xrow + (size_t)(t + 1) * 256);   // prefetch next x (NO drain)
  }

  // ---- head: one WG per group computes out = h_T @ W_out^T + b_out ----
  if (wgN == 0) {
    {
      const u32* hp = cnt + (lane & 3) * 64;
      int guard = 0;
      for (;;) {
        u32 v = poll_sc(hp);
        if (__all((int)(v >= 8u * NSTEPS))) break;
        if (++guard > (1 << 20)) break;
      }
    }
    const char* src = grpsl + SLOT_BYTES;        // slot 255&1 = 1
    int b = tid >> 2, q = tid & 3;
    float s = 0.f;
    #pragma unroll
    for (int j16 = 0; j16 < 8; ++j16) {
      int nblk = q * 8 + j16;                    // wgN' block
      const char* p = src + nblk * 2048 + b * 32;
      u32x4 w0 = ld16_sc_wait(p);
      u32x4 w1 = ld16_sc_wait(p + 16);
      #pragma unroll
      for (int d = 0; d < 4; ++d) {
        int jb = q * 128 + j16 * 16 + d * 2;
        s += bf2f((u16)(w0[d] & 0xffff)) * W_out[jb];
        s += bf2f((u16)(w0[d] >> 16))    * W_out[jb + 1];
        s += bf2f((u16)(w1[d] & 0xffff)) * W_out[jb + 8];
        s += bf2f((u16)(w1[d] >> 16))    * W_out[jb + 9];
      }
    }
    s += __shfl_xor(s, 1);
    s += __shfl_xor(s, 2);
    if (q == 0) out[grp * 64 + b] = s + b_out[0];
  }
}

extern "C" void kernel_launch(void* const* d_in, const int* in_sizes, int n_in,
                              void* d_out, int out_size, void* d_ws, size_t ws_size,
                              hipStream_t stream) {
  (void)in_sizes; (void)n_in; (void)out_size; (void)ws_size;
  const float* x     = (const float*)d_in[0];
  const float* W_ih  = (const float*)d_in[1];
  const float* W_hh  = (const float*)d_in[2];
  const float* b_ih  = (const float*)d_in[3];
  const float* b_hh  = (const float*)d_in[4];
  const float* W_out = (const float*)d_in[5];
  const float* b_out = (const float*)d_in[6];
  char* ws = (char*)d_ws;

  // zero h-exchange slots + spread counters (re-runs every graph replay)
  hipMemsetAsync(ws + SL_OFF, 0, 2u * SLOT_BYTES + 8192u, stream);
  cvt_x<<<32768, 256, 0, stream>>>(x, (u16*)ws);
  lstm_main<<<256, 256, 0, stream>>>((const u16*)ws, W_ih, W_hh, b_ih, b_hh,
                                     W_out, b_out, (float*)d_out, ws);
}